// Round 19
// baseline (182.688 us; speedup 1.0000x reference)
//
#include <hip/hip_runtime.h>

constexpr int N_NODES = 50000;
constexpr int IN_C    = 128;
constexpr int HID_C   = 128;
constexpr int OUT_C   = 64;
constexpr int N_EDGES = 800000;
constexpr int N_LABEL = 200000;
constexpr float BN_EPS = 1e-5f;
constexpr int NCHUNK  = (N_NODES + 256) / 256 + 1;   // 196 chunks cover 50176 >= 50001
constexpr int BN_BLOCKS = 512;
constexpr int BN_RPH    = 13;    // rows per half-wave: 512*8*13 = 53248 >= 50000

typedef __attribute__((ext_vector_type(8))) short bf16x8;
typedef __attribute__((ext_vector_type(4))) float f32x4;

// ---- bf16 helpers (plain ushort storage) ----------------------------------
__device__ __forceinline__ float bf_lo(unsigned v) {
    union { unsigned u; float f; } t; t.u = v << 16; return t.f;
}
__device__ __forceinline__ float bf_hi(unsigned v) {
    union { unsigned u; float f; } t; t.u = v & 0xffff0000u; return t.f;
}
__device__ __forceinline__ unsigned short f2bf(float f) {
    union { float f; unsigned u; } t; t.f = f;
    unsigned r = t.u + 0x7fffu + ((t.u >> 16) & 1u);   // round-nearest-even
    return (unsigned short)(r >> 16);
}
__device__ __forceinline__ unsigned pack2bf(float a, float b) {
    return (unsigned)f2bf(a) | ((unsigned)f2bf(b) << 16);
}

// ---- fp8 e4m3 helpers (bit tricks; no HW intrinsics) ----------------------
// raw decode: value scaled by 2^-120 (fold the 2^120 into the mean divisor)
__device__ __forceinline__ float fp8_raw(unsigned b) {
    union { unsigned u; float f; } t;
    t.u = ((b & 0x80u) << 24) | ((b & 0x7Fu) << 20);
    return t.f;
}
__device__ __forceinline__ unsigned f32_fp8(float x) {
    union { float f; unsigned u; } t; t.f = x * 0x1p-120f;
    unsigned au = t.u & 0x7FFFFFFFu;
    unsigned r = au + 0x7FFFFu + ((au >> 20) & 1u);
    return ((r >> 20) & 0x7Fu) | ((t.u >> 24) & 0x80u);
}

// ---------------------------------------------------------------------------
// setup_kernel: zero ideg AND pack both weight matrices into MFMA frag order.
//   Bp[((nt*4 + kt)*64 + l)*8 + j] = B[kt*32 + (l>>4)*8 + j][nt*16 + (l&15)]
__global__ void setup_kernel(int* __restrict__ ideg,
                             const float* __restrict__ W1l, const float* __restrict__ W1r,
                             short* __restrict__ Bp1,
                             const float* __restrict__ W2l, const float* __restrict__ W2r,
                             short* __restrict__ Bp2) {
    int i = blockIdx.x * 256 + threadIdx.x;
    if (i < 50432) ideg[i] = 0;
    int j = i & 7;
    int l = (i >> 3) & 63;
    int ktnt = i >> 9;
    int kt = ktnt & 3;
    int nl = l & 15, kk = ((l >> 4) << 3) + j;
    int k = kt * 32 + kk;
    if (i < 32768) {           // Bp1: C=256, HALF=128
        int nt = ktnt >> 2;
        int n = nt * 16 + nl;
        float v = (n < 128) ? W1l[k * 128 + n] : W1r[k * 128 + (n - 128)];
        Bp1[i] = (short)f2bf(v);
    }
    if (i < 16384) {           // Bp2: C=128, HALF=64
        int nt = ktnt >> 2;
        int n = nt * 16 + nl;
        float v = (n < 64) ? W2l[k * 64 + n] : W2r[k * 64 + (n - 64)];
        Bp2[i] = (short)f2bf(v);
    }
}

// ---------------------------------------------------------------------------
// CSR build step 1: histogram of dst + per-edge rank (atomicAdd return)
__global__ void hist_kernel(const int* __restrict__ dst, int* __restrict__ deg,
                            int* __restrict__ rank) {
    int e = blockIdx.x * blockDim.x + threadIdx.x;
    if (e < N_EDGES) rank[e] = atomicAdd(&deg[dst[e]], 1);
}

// CSR build step 2a: per-chunk sums (deg is zero-padded past N_NODES)
__global__ void chunk_sum_kernel(const int* __restrict__ deg, int* __restrict__ bsum) {
    int i = blockIdx.x * 256 + threadIdx.x;
    int v = deg[i];
    #pragma unroll
    for (int o = 32; o > 0; o >>= 1) v += __shfl_down(v, o, 64);
    __shared__ int ws[4];
    if ((threadIdx.x & 63) == 0) ws[threadIdx.x >> 6] = v;
    __syncthreads();
    if (threadIdx.x == 0) bsum[blockIdx.x] = ws[0] + ws[1] + ws[2] + ws[3];
}

// CSR build step 2b: exclusive scan of the chunk sums (single tiny block)
__global__ void scan_bsum_kernel(const int* __restrict__ bsum, int* __restrict__ boff) {
    __shared__ int t[256];
    int tid = threadIdx.x;
    t[tid] = (tid < NCHUNK) ? bsum[tid] : 0;
    __syncthreads();
    for (int o = 1; o < 256; o <<= 1) {
        int v = t[tid];
        int add = (tid >= o) ? t[tid - o] : 0;
        __syncthreads();
        t[tid] = v + add;
        __syncthreads();
    }
    boff[tid] = (tid == 0) ? 0 : t[tid - 1];
}

// CSR build step 2c: per-chunk exclusive scan + chunk offset -> off
__global__ void scan_final_kernel(const int* __restrict__ deg, const int* __restrict__ boff,
                                  int* __restrict__ off) {
    __shared__ int t[256];
    int tid = threadIdx.x;
    int i = blockIdx.x * 256 + tid;
    int d = deg[i];
    t[tid] = d;
    __syncthreads();
    for (int o = 1; o < 256; o <<= 1) {
        int v = t[tid];
        int add = (tid >= o) ? t[tid - o] : 0;
        __syncthreads();
        t[tid] = v + add;
        __syncthreads();
    }
    int excl = boff[blockIdx.x] + t[tid] - d;
    if (i <= N_NODES) off[i] = excl;       // off[N_NODES] == N_EDGES (deg pad = 0)
}

// CSR build step 3: place src ids (atomic-free; ushort since ids < 65536)
__global__ void scatter_kernel(const int* __restrict__ src, const int* __restrict__ dst,
                               const int* __restrict__ off, const int* __restrict__ rank,
                               unsigned short* __restrict__ csr_src) {
    int e = blockIdx.x * blockDim.x + threadIdx.x;
    if (e < N_EDGES) csr_src[off[dst[e]] + rank[e]] = (unsigned short)src[e];
}

// ---------------------------------------------------------------------------
// MFMA GEMM: 512 threads = 8 waves, 128 rows/block; full unroll inner loop;
// B staged via pure 16B memcpy.
//   MODE 0 (conv1): A = x (f32), C=256; cols 0..127 -> y1 (fp8 e4m3),
//                   cols 128..255 -> h = . + b1 (bf16)
//   MODE 1 (conv2): A = h (bf16) with fused BN+ReLU, C=128;
//                   cols 0..63 -> t2l (fp8); cols 64..127 -> t2r = . + b2 (bf16)
template <int MODE>
__global__ __launch_bounds__(512) void mfma_gemm(
    const void* __restrict__ Ain, const short* __restrict__ Bp,
    const float* __restrict__ bias, const float* __restrict__ ss,
    unsigned char* __restrict__ outFp8,      // MODE0: y1, MODE1: t2l
    unsigned short* __restrict__ outH16)     // MODE0: h,  MODE1: t2r
{
    constexpr int C    = (MODE == 0) ? 256 : 128;
    constexpr int NT   = C / 16;
    constexpr int HALF = C / 2;
    constexpr int CHUNKS = 128 * C / 8;     // float4 chunks: 4096 / 2048

    __shared__ short sB[128 * C];           // 64 KB (MODE0) / 32 KB (MODE1)

    // ---- stage pre-packed B: straight 16B-per-lane memcpy ----
    {
        const float4* bp4 = reinterpret_cast<const float4*>(Bp);
        float4* sb4 = reinterpret_cast<float4*>(sB);
        #pragma unroll
        for (int i = 0; i < CHUNKS / 512; ++i)
            sb4[i * 512 + threadIdx.x] = bp4[i * 512 + threadIdx.x];
    }

    int tid  = threadIdx.x;
    int wid  = tid >> 6, lane = tid & 63;
    int m0   = blockIdx.x * 128 + wid * 16;
    int row  = m0 + (lane & 15);
    int rowc = (row < N_NODES) ? row : (N_NODES - 1);
    int kbase = (lane >> 4) * 8;

    // ---- A fragments ----
    bf16x8 a[4];
    #pragma unroll
    for (int kt = 0; kt < 4; ++kt) {
        int k0 = kt * 32 + kbase;
        float v[8];
        if (MODE == 0) {
            const float* ap = (const float*)Ain + (long long)rowc * 128;
            float4 u0 = *reinterpret_cast<const float4*>(ap + k0);
            float4 u1 = *reinterpret_cast<const float4*>(ap + k0 + 4);
            v[0]=u0.x; v[1]=u0.y; v[2]=u0.z; v[3]=u0.w;
            v[4]=u1.x; v[5]=u1.y; v[6]=u1.z; v[7]=u1.w;
        } else {
            const unsigned short* ap = (const unsigned short*)Ain + (long long)rowc * 128;
            uint4 w = *reinterpret_cast<const uint4*>(ap + k0);
            v[0]=bf_lo(w.x); v[1]=bf_hi(w.x); v[2]=bf_lo(w.y); v[3]=bf_hi(w.y);
            v[4]=bf_lo(w.z); v[5]=bf_hi(w.z); v[6]=bf_lo(w.w); v[7]=bf_hi(w.w);
            float4 s0 = *reinterpret_cast<const float4*>(ss + k0);
            float4 s1 = *reinterpret_cast<const float4*>(ss + k0 + 4);
            float4 t0 = *reinterpret_cast<const float4*>(ss + 128 + k0);
            float4 t1 = *reinterpret_cast<const float4*>(ss + 128 + k0 + 4);
            float sc[8] = {s0.x, s0.y, s0.z, s0.w, s1.x, s1.y, s1.z, s1.w};
            float sh[8] = {t0.x, t0.y, t0.z, t0.w, t1.x, t1.y, t1.z, t1.w};
            #pragma unroll
            for (int j = 0; j < 8; ++j) v[j] = fmaxf(v[j] * sc[j] + sh[j], 0.f);
        }
        #pragma unroll
        for (int j = 0; j < 8; ++j) a[kt][j] = (short)f2bf(v[j]);
    }

    __syncthreads();

    // ---- MFMA main loop: FULL unroll (compiler pipelines ds_reads) ----
    f32x4 acc[NT] = {};
    #pragma unroll
    for (int kt = 0; kt < 4; ++kt) {
        #pragma unroll
        for (int nt = 0; nt < NT; ++nt) {
            bf16x8 b = *reinterpret_cast<const bf16x8*>(
                sB + ((((nt << 2) + kt) * 64 + lane) << 3));
            acc[nt] = __builtin_amdgcn_mfma_f32_16x16x32_bf16(a[kt], b, acc[nt], 0, 0, 0);
        }
    }

    // ---- epilogue (D: lane l, reg j -> D[m0+(l>>4)*4+j][nt*16+(l&15)]) ----
    int r0 = m0 + ((lane >> 4) << 2);
    int nl = lane & 15;
    #pragma unroll
    for (int nt = 0; nt < NT; ++nt) {
        int col = nt * 16 + nl;
        float bb = (col >= HALF) ? bias[col - HALF] : 0.f;
        #pragma unroll
        for (int j = 0; j < 4; ++j) {
            int r = r0 + j;
            if (r >= N_NODES) continue;
            float vv = acc[nt][j];
            if (MODE == 0) {
                if (col < HALF) outFp8[(long long)r * 128 + col] = (unsigned char)f32_fp8(vv);
                else            outH16[(long long)r * 128 + (col - HALF)] = f2bf(vv + bb);
            } else {
                if (col < HALF) outFp8[(long long)r * 64 + col] = (unsigned char)f32_fp8(vv);
                else            outH16[(long long)r * 64 + (col - HALF)] = f2bf(vv + bb);
            }
        }
    }
}

// ---------------------------------------------------------------------------
// conv1 aggregate: h[n] += mean_{s in N(n)} y1[s]; y1 fp8 (128 B/row),
// h bf16 (256 B/row). Quarter-wave per edge: 16 lanes x uint2 (8 B = 8 ch).
// fp8 decoded RAW (2^-120 scale folded into inv) -> one less VALU mul/elem.
__global__ __launch_bounds__(256) void agg_mean_add_128(
    const int* __restrict__ off, const unsigned short* __restrict__ csr_src,
    const uint2* __restrict__ y8, uint4* __restrict__ h4) {
    int node = blockIdx.x * 4 + (threadIdx.x >> 6);
    if (node >= N_NODES) return;
    int lane = threadIdx.x & 63;
    int grp  = lane >> 4;          // 0..3: which edge of the quad
    int c8   = lane & 15;          // uint2 idx: channels c8*8 .. c8*8+7
    int beg = off[node], end = off[node + 1];
    float s[8] = {0.f, 0.f, 0.f, 0.f, 0.f, 0.f, 0.f, 0.f};
    int i = beg + grp;
    for (; i + 4 < end; i += 8) {
        uint2 v0 = y8[(long long)csr_src[i]     * 16 + c8];
        uint2 v1 = y8[(long long)csr_src[i + 4] * 16 + c8];
        #pragma unroll
        for (int j = 0; j < 4; ++j) {
            s[j]     += fp8_raw((v0.x >> (8 * j)) & 0xFFu) + fp8_raw((v1.x >> (8 * j)) & 0xFFu);
            s[4 + j] += fp8_raw((v0.y >> (8 * j)) & 0xFFu) + fp8_raw((v1.y >> (8 * j)) & 0xFFu);
        }
    }
    for (; i < end; i += 4) {
        uint2 v0 = y8[(long long)csr_src[i] * 16 + c8];
        #pragma unroll
        for (int j = 0; j < 4; ++j) {
            s[j]     += fp8_raw((v0.x >> (8 * j)) & 0xFFu);
            s[4 + j] += fp8_raw((v0.y >> (8 * j)) & 0xFFu);
        }
    }
    #pragma unroll
    for (int j = 0; j < 8; ++j) {
        s[j] += __shfl_down(s[j], 16);
        s[j] += __shfl_down(s[j], 32);
    }
    if (grp == 0) {
        float inv = (end > beg) ? 0x1p120f / (float)(end - beg) : 0.f;
        uint4 hv = h4[(long long)node * 16 + c8];   // 8 bf16 channels
        hv.x = pack2bf(bf_lo(hv.x) + s[0] * inv, bf_hi(hv.x) + s[1] * inv);
        hv.y = pack2bf(bf_lo(hv.y) + s[2] * inv, bf_hi(hv.y) + s[3] * inv);
        hv.z = pack2bf(bf_lo(hv.z) + s[4] * inv, bf_hi(hv.z) + s[5] * inv);
        hv.w = pack2bf(bf_lo(hv.w) + s[6] * inv, bf_hi(hv.w) + s[7] * inv);
        h4[(long long)node * 16 + c8] = hv;
    }
}

// ---------------------------------------------------------------------------
// BN stats stage A (h bf16): half-wave owns 13 rows; load-all-then-reduce.
__global__ __launch_bounds__(256) void bn_stats_partial(
    const uint2* __restrict__ h2, float* __restrict__ partial) {
    int tid = threadIdx.x;
    int wid = tid >> 6;
    int lane = tid & 63;
    int half = lane >> 5;          // 0/1
    int c4   = lane & 31;          // uint2 idx: channels 4*c4 .. 4*c4+3
    int hw   = (blockIdx.x << 3) + (wid << 1) + half;
    int r0   = hw * BN_RPH;

    uint2 v[BN_RPH];
    #pragma unroll
    for (int j = 0; j < BN_RPH; ++j) {
        int r = r0 + j;
        v[j] = (r < N_NODES) ? h2[(long long)r * 32 + c4] : uint2{0u, 0u};
    }
    float s[4] = {0.f, 0.f, 0.f, 0.f}, q[4] = {0.f, 0.f, 0.f, 0.f};
    #pragma unroll
    for (int j = 0; j < BN_RPH; ++j) {
        float a0 = bf_lo(v[j].x), a1 = bf_hi(v[j].x);
        float a2 = bf_lo(v[j].y), a3 = bf_hi(v[j].y);
        s[0] += a0; q[0] += a0 * a0;
        s[1] += a1; q[1] += a1 * a1;
        s[2] += a2; q[2] += a2 * a2;
        s[3] += a3; q[3] += a3 * a3;
    }
    #pragma unroll
    for (int j = 0; j < 4; ++j) {
        s[j] += __shfl_down(s[j], 32);
        q[j] += __shfl_down(q[j], 32);
    }
    __shared__ float ls[4][32][8];
    if (half == 0) {
        #pragma unroll
        for (int j = 0; j < 4; ++j) { ls[wid][c4][j] = s[j]; ls[wid][c4][4 + j] = q[j]; }
    }
    __syncthreads();
    if (tid < 32) {
        #pragma unroll
        for (int j = 0; j < 8; ++j) {
            float a = ls[0][tid][j] + ls[1][tid][j] + ls[2][tid][j] + ls[3][tid][j];
            partial[blockIdx.x * 256 + (j < 4 ? 0 : 128) + tid * 4 + (j & 3)] = a;
        }
    }
}

// BN stats stage B + finalize fused (single block; removes sums buffer,
// its zeroing, and one launch).
__global__ void bn_reduce_finalize(const float* __restrict__ partial,
                                   const float* __restrict__ gamma,
                                   const float* __restrict__ beta,
                                   float* __restrict__ ss) {
    int t = threadIdx.x;
    float a = 0.f;
    #pragma unroll 16
    for (int b = 0; b < BN_BLOCKS; ++b)
        a += partial[b * 256 + t];
    __shared__ float tot[256];
    tot[t] = a;
    __syncthreads();
    if (t < 128) {
        float mu  = tot[t] * (1.0f / N_NODES);
        float var = tot[128 + t] * (1.0f / N_NODES) - mu * mu;
        float sc = gamma[t] * rsqrtf(var + BN_EPS);
        ss[t] = sc;
        ss[128 + t] = beta[t] - mu * sc;
    }
}

// ---------------------------------------------------------------------------
// conv2 aggregate: z[n] = bf16( mean t2l[N(n)] + t2r[n] ); t2l fp8 (64 B/row),
// t2r bf16, z bf16 (fp8 z failed R18: dot of two fp8 operands compounds err).
__global__ __launch_bounds__(256) void agg_mean_add_64(
    const int* __restrict__ off, const unsigned short* __restrict__ csr_src,
    const unsigned* __restrict__ t2l4, const uint2* __restrict__ t2r2,
    uint2* __restrict__ z2) {
    int node = blockIdx.x * 4 + (threadIdx.x >> 6);
    if (node >= N_NODES) return;
    int lane = threadIdx.x & 63;
    int grp  = lane >> 4;          // 0..3: which edge of the quad
    int c4   = lane & 15;          // uint idx: channels c4*4 .. c4*4+3
    int beg = off[node], end = off[node + 1];
    float s[4] = {0.f, 0.f, 0.f, 0.f};
    int i = beg + grp;
    for (; i + 4 < end; i += 8) {
        unsigned v0 = t2l4[(long long)csr_src[i]     * 16 + c4];
        unsigned v1 = t2l4[(long long)csr_src[i + 4] * 16 + c4];
        #pragma unroll
        for (int j = 0; j < 4; ++j)
            s[j] += fp8_raw((v0 >> (8 * j)) & 0xFFu) + fp8_raw((v1 >> (8 * j)) & 0xFFu);
    }
    for (; i < end; i += 4) {
        unsigned v0 = t2l4[(long long)csr_src[i] * 16 + c4];
        #pragma unroll
        for (int j = 0; j < 4; ++j)
            s[j] += fp8_raw((v0 >> (8 * j)) & 0xFFu);
    }
    #pragma unroll
    for (int j = 0; j < 4; ++j) {
        s[j] += __shfl_down(s[j], 16);
        s[j] += __shfl_down(s[j], 32);
    }
    if (grp == 0) {
        float inv = (end > beg) ? 0x1p120f / (float)(end - beg) : 0.f;
        uint2 rv = t2r2[(long long)node * 16 + c4];
        uint2 o;
        o.x = pack2bf(bf_lo(rv.x) + s[0] * inv, bf_hi(rv.x) + s[1] * inv);
        o.y = pack2bf(bf_lo(rv.y) + s[2] * inv, bf_hi(rv.y) + s[3] * inv);
        z2[(long long)node * 16 + c4] = o;
    }
}

// ---------------------------------------------------------------------------
// out[l] = dot(z[src_l], z[dst_l]) over 64 bf16 channels; 16 lanes per label
__global__ void edge_dot_kernel(const int* __restrict__ eli,
                                const unsigned short* __restrict__ z,
                                float* __restrict__ out) {
    long long gid = (long long)blockIdx.x * blockDim.x + threadIdx.x;
    int l = (int)(gid >> 4);
    int lane = (int)(gid & 15);
    if (l >= N_LABEL) return;
    int s = eli[l];
    int d = eli[N_LABEL + l];
    uint2 av = *reinterpret_cast<const uint2*>(z + (long long)s * 64 + lane * 4);
    uint2 bv = *reinterpret_cast<const uint2*>(z + (long long)d * 64 + lane * 4);
    float p = bf_lo(av.x) * bf_lo(bv.x) + bf_hi(av.x) * bf_hi(bv.x)
            + bf_lo(av.y) * bf_lo(bv.y) + bf_hi(av.y) * bf_hi(bv.y);
    p += __shfl_down(p, 8, 16);
    p += __shfl_down(p, 4, 16);
    p += __shfl_down(p, 2, 16);
    p += __shfl_down(p, 1, 16);
    if (lane == 0) out[l] = p;
}

// ---------------------------------------------------------------------------
extern "C" void kernel_launch(void* const* d_in, const int* in_sizes, int n_in,
                              void* d_out, int out_size, void* d_ws, size_t ws_size,
                              hipStream_t stream) {
    const float* x     = (const float*)d_in[0];
    const int*   ei    = (const int*)d_in[1];   // [2, 800000]: row0 src, row1 dst
    const int*   eli   = (const int*)d_in[2];   // [2, 200000]
    const float* W1l   = (const float*)d_in[3];
    const float* W1r   = (const float*)d_in[4];
    const float* b1    = (const float*)d_in[5];
    const float* gamma = (const float*)d_in[6];
    const float* beta  = (const float*)d_in[7];
    const float* W2l   = (const float*)d_in[8];
    const float* W2r   = (const float*)d_in[9];
    const float* b2    = (const float*)d_in[10];
    float* out = (float*)d_out;

    const int* src  = ei;
    const int* dstv = ei + N_EDGES;

    // workspace layout (ints first; all region starts 16B-aligned)
    int* ideg  = (int*)d_ws;             // 50432 (zero-padded to NCHUNK*256)
    int* ioff  = ideg + 50432;           // 50056
    int* ibsum = ioff + 50056;           // 256
    int* iboff = ibsum + 256;            // 256
    unsigned short* icsr = (unsigned short*)(iboff + 256);   // 800000 ushort (1.6 MB)
    unsigned char*  y1  = (unsigned char*)(icsr + 800000);   // 6.4M fp8  (6.4 MB)
    unsigned short* h   = (unsigned short*)(y1 + 6400000);   // 6.4M bf16 (12.8 MB)
    unsigned char*  t2l = (unsigned char*)(h + 6400000);     // 3.2M fp8  (3.2 MB)
    unsigned short* t2r = (unsigned short*)(t2l + 3200000);  // 3.2M bf16
    unsigned short* z   = t2r + 3200000;                     // 3.2M bf16
    float* ss   = (float*)(z + 3200000);                     // 256
    short* Bp1  = (short*)(ss + 256);                        // 32768 bf16 (128x256)
    short* Bp2  = Bp1 + 32768;                               // 16384 bf16 (128x128)
    float* bnpart = (float*)(Bp2 + 16384);                   // 512*256 f32 = 512 KB
    // rank aliases y1's region (3.2 MB < 6.4 MB); consumed by scatter_kernel
    // before mfma_gemm<0> writes y1 (stream order).
    int* irank = (int*)y1;

    // ---- setup: zero ideg, pack Bp1+Bp2 (1 launch) ----
    setup_kernel<<<(50432 + 255) / 256, 256, 0, stream>>>(
        ideg, W1l, W1r, Bp1, W2l, W2r, Bp2);

    // ---- CSR build ----
    hist_kernel<<<(N_EDGES + 255) / 256, 256, 0, stream>>>(dstv, ideg, irank);
    chunk_sum_kernel<<<NCHUNK, 256, 0, stream>>>(ideg, ibsum);
    scan_bsum_kernel<<<1, 256, 0, stream>>>(ibsum, iboff);
    scan_final_kernel<<<NCHUNK, 256, 0, stream>>>(ideg, iboff, ioff);
    scatter_kernel<<<(N_EDGES + 255) / 256, 256, 0, stream>>>(src, dstv, ioff, irank, icsr);

    const int GEMM_GRID = (N_NODES + 127) / 128;   // 391

    // ---- conv1: y1(fp8) = x@W1l, h(bf16) = x@W1r + b1; then h += mean(y1) --
    mfma_gemm<0><<<GEMM_GRID, 512, 0, stream>>>(x, Bp1, b1, ss, y1, h);
    agg_mean_add_128<<<(N_NODES + 3) / 4, 256, 0, stream>>>(
        ioff, icsr, (const uint2*)y1, (uint4*)h);

    // ---- batchnorm stats (partial -> fused reduce+finalize) ----
    bn_stats_partial<<<BN_BLOCKS, 256, 0, stream>>>((const uint2*)h, bnpart);
    bn_reduce_finalize<<<1, 256, 0, stream>>>(bnpart, gamma, beta, ss);

    // ---- conv2: t2l(fp8) = relu(bn(h))@W2l, t2r(bf16) = relu(bn(h))@W2r + b2
    mfma_gemm<1><<<GEMM_GRID, 512, 0, stream>>>(h, Bp2, b2, ss, t2l, t2r);
    agg_mean_add_64<<<(N_NODES + 3) / 4, 256, 0, stream>>>(
        ioff, icsr, (const unsigned*)t2l, (const uint2*)t2r, (uint2*)z);

    // ---- edge dot readout ----
    edge_dot_kernel<<<((long long)N_LABEL * 16 + 255) / 256, 256, 0, stream>>>(eli, z, out);
}

// Round 20
// 172.842 us; speedup vs baseline: 1.0570x; 1.0570x over previous
//
#include <hip/hip_runtime.h>

constexpr int N_NODES = 50000;
constexpr int IN_C    = 128;
constexpr int HID_C   = 128;
constexpr int OUT_C   = 64;
constexpr int N_EDGES = 800000;
constexpr int N_LABEL = 200000;
constexpr float BN_EPS = 1e-5f;
constexpr int NCHUNK  = (N_NODES + 256) / 256 + 1;   // 196 chunks cover 50176 >= 50001
constexpr int BN_BLOCKS = 512;
constexpr int BN_RPH    = 13;    // rows per half-wave: 512*8*13 = 53248 >= 50000

typedef __attribute__((ext_vector_type(8))) short bf16x8;
typedef __attribute__((ext_vector_type(4))) float f32x4;

// ---- bf16 helpers (plain ushort storage) ----------------------------------
__device__ __forceinline__ float bf_lo(unsigned v) {
    union { unsigned u; float f; } t; t.u = v << 16; return t.f;
}
__device__ __forceinline__ float bf_hi(unsigned v) {
    union { unsigned u; float f; } t; t.u = v & 0xffff0000u; return t.f;
}
__device__ __forceinline__ unsigned short f2bf(float f) {
    union { float f; unsigned u; } t; t.f = f;
    unsigned r = t.u + 0x7fffu + ((t.u >> 16) & 1u);   // round-nearest-even
    return (unsigned short)(r >> 16);
}
__device__ __forceinline__ unsigned pack2bf(float a, float b) {
    return (unsigned)f2bf(a) | ((unsigned)f2bf(b) << 16);
}

// ---- fp8 e4m3 helpers (bit tricks; no HW intrinsics) ----------------------
__device__ __forceinline__ float fp8_f32(unsigned b) {
    union { unsigned u; float f; } t;
    t.u = ((b & 0x80u) << 24) | ((b & 0x7Fu) << 20);
    return t.f * 0x1p120f;
}
__device__ __forceinline__ unsigned f32_fp8(float x) {
    union { float f; unsigned u; } t; t.f = x * 0x1p-120f;
    unsigned au = t.u & 0x7FFFFFFFu;
    unsigned r = au + 0x7FFFFu + ((au >> 20) & 1u);
    return ((r >> 20) & 0x7Fu) | ((t.u >> 24) & 0x80u);
}

// ---------------------------------------------------------------------------
// setup_kernel: zero ideg+sums AND pack both weight matrices into MFMA
// fragment order.
//   Bp[((nt*4 + kt)*64 + l)*8 + j] = B[kt*32 + (l>>4)*8 + j][nt*16 + (l&15)]
__global__ void setup_kernel(int* __restrict__ ideg, float* __restrict__ sums,
                             const float* __restrict__ W1l, const float* __restrict__ W1r,
                             short* __restrict__ Bp1,
                             const float* __restrict__ W2l, const float* __restrict__ W2r,
                             short* __restrict__ Bp2) {
    int i = blockIdx.x * 256 + threadIdx.x;
    if (i < 50432) ideg[i] = 0;
    if (i < 256) sums[i] = 0.f;
    int j = i & 7;
    int l = (i >> 3) & 63;
    int ktnt = i >> 9;
    int kt = ktnt & 3;
    int nl = l & 15, kk = ((l >> 4) << 3) + j;
    int k = kt * 32 + kk;
    if (i < 32768) {           // Bp1: C=256, HALF=128
        int nt = ktnt >> 2;
        int n = nt * 16 + nl;
        float v = (n < 128) ? W1l[k * 128 + n] : W1r[k * 128 + (n - 128)];
        Bp1[i] = (short)f2bf(v);
    }
    if (i < 16384) {           // Bp2: C=128, HALF=64
        int nt = ktnt >> 2;
        int n = nt * 16 + nl;
        float v = (n < 64) ? W2l[k * 64 + n] : W2r[k * 64 + (n - 64)];
        Bp2[i] = (short)f2bf(v);
    }
}

// ---------------------------------------------------------------------------
// CSR build step 1: histogram of dst + per-edge rank (atomicAdd return)
__global__ void hist_kernel(const int* __restrict__ dst, int* __restrict__ deg,
                            int* __restrict__ rank) {
    int e = blockIdx.x * blockDim.x + threadIdx.x;
    if (e < N_EDGES) rank[e] = atomicAdd(&deg[dst[e]], 1);
}

// CSR build step 2a: per-chunk sums (deg is zero-padded past N_NODES)
__global__ void chunk_sum_kernel(const int* __restrict__ deg, int* __restrict__ bsum) {
    int i = blockIdx.x * 256 + threadIdx.x;
    int v = deg[i];
    #pragma unroll
    for (int o = 32; o > 0; o >>= 1) v += __shfl_down(v, o, 64);
    __shared__ int ws[4];
    if ((threadIdx.x & 63) == 0) ws[threadIdx.x >> 6] = v;
    __syncthreads();
    if (threadIdx.x == 0) bsum[blockIdx.x] = ws[0] + ws[1] + ws[2] + ws[3];
}

// CSR build step 2b: exclusive scan of the chunk sums (single tiny block)
__global__ void scan_bsum_kernel(const int* __restrict__ bsum, int* __restrict__ boff) {
    __shared__ int t[256];
    int tid = threadIdx.x;
    t[tid] = (tid < NCHUNK) ? bsum[tid] : 0;
    __syncthreads();
    for (int o = 1; o < 256; o <<= 1) {
        int v = t[tid];
        int add = (tid >= o) ? t[tid - o] : 0;
        __syncthreads();
        t[tid] = v + add;
        __syncthreads();
    }
    boff[tid] = (tid == 0) ? 0 : t[tid - 1];
}

// CSR build step 2c: per-chunk exclusive scan + chunk offset -> off
__global__ void scan_final_kernel(const int* __restrict__ deg, const int* __restrict__ boff,
                                  int* __restrict__ off) {
    __shared__ int t[256];
    int tid = threadIdx.x;
    int i = blockIdx.x * 256 + tid;
    int d = deg[i];
    t[tid] = d;
    __syncthreads();
    for (int o = 1; o < 256; o <<= 1) {
        int v = t[tid];
        int add = (tid >= o) ? t[tid - o] : 0;
        __syncthreads();
        t[tid] = v + add;
        __syncthreads();
    }
    int excl = boff[blockIdx.x] + t[tid] - d;
    if (i <= N_NODES) off[i] = excl;       // off[N_NODES] == N_EDGES (deg pad = 0)
}

// CSR build step 3: place src ids (atomic-free; ushort since ids < 65536)
__global__ void scatter_kernel(const int* __restrict__ src, const int* __restrict__ dst,
                               const int* __restrict__ off, const int* __restrict__ rank,
                               unsigned short* __restrict__ csr_src) {
    int e = blockIdx.x * blockDim.x + threadIdx.x;
    if (e < N_EDGES) csr_src[off[dst[e]] + rank[e]] = (unsigned short)src[e];
}

// ---------------------------------------------------------------------------
// MFMA GEMM: 512 threads = 8 waves, 128 rows/block; full unroll inner loop;
// B staged via pure 16B memcpy.
//   MODE 0 (conv1): A = x (f32), C=256; cols 0..127 -> y1 (fp8 e4m3),
//                   cols 128..255 -> h = . + b1 (bf16)
//   MODE 1 (conv2): A = h (bf16) with fused BN+ReLU, C=128;
//                   cols 0..63 -> t2l (fp8 e4m3); cols 64..127 -> t2r = . + b2 (bf16)
template <int MODE>
__global__ __launch_bounds__(512) void mfma_gemm(
    const void* __restrict__ Ain, const short* __restrict__ Bp,
    const float* __restrict__ bias, const float* __restrict__ ss,
    unsigned char* __restrict__ outFp8,      // MODE0: y1, MODE1: t2l
    unsigned short* __restrict__ outH16)     // MODE0: h,  MODE1: t2r
{
    constexpr int C    = (MODE == 0) ? 256 : 128;
    constexpr int NT   = C / 16;
    constexpr int HALF = C / 2;
    constexpr int CHUNKS = 128 * C / 8;     // float4 chunks: 4096 / 2048

    __shared__ short sB[128 * C];           // 64 KB (MODE0) / 32 KB (MODE1)

    // ---- stage pre-packed B: straight 16B-per-lane memcpy ----
    {
        const float4* bp4 = reinterpret_cast<const float4*>(Bp);
        float4* sb4 = reinterpret_cast<float4*>(sB);
        #pragma unroll
        for (int i = 0; i < CHUNKS / 512; ++i)
            sb4[i * 512 + threadIdx.x] = bp4[i * 512 + threadIdx.x];
    }

    int tid  = threadIdx.x;
    int wid  = tid >> 6, lane = tid & 63;
    int m0   = blockIdx.x * 128 + wid * 16;
    int row  = m0 + (lane & 15);
    int rowc = (row < N_NODES) ? row : (N_NODES - 1);
    int kbase = (lane >> 4) * 8;

    // ---- A fragments ----
    bf16x8 a[4];
    #pragma unroll
    for (int kt = 0; kt < 4; ++kt) {
        int k0 = kt * 32 + kbase;
        float v[8];
        if (MODE == 0) {
            const float* ap = (const float*)Ain + (long long)rowc * 128;
            float4 u0 = *reinterpret_cast<const float4*>(ap + k0);
            float4 u1 = *reinterpret_cast<const float4*>(ap + k0 + 4);
            v[0]=u0.x; v[1]=u0.y; v[2]=u0.z; v[3]=u0.w;
            v[4]=u1.x; v[5]=u1.y; v[6]=u1.z; v[7]=u1.w;
        } else {
            const unsigned short* ap = (const unsigned short*)Ain + (long long)rowc * 128;
            uint4 w = *reinterpret_cast<const uint4*>(ap + k0);
            v[0]=bf_lo(w.x); v[1]=bf_hi(w.x); v[2]=bf_lo(w.y); v[3]=bf_hi(w.y);
            v[4]=bf_lo(w.z); v[5]=bf_hi(w.z); v[6]=bf_lo(w.w); v[7]=bf_hi(w.w);
            float4 s0 = *reinterpret_cast<const float4*>(ss + k0);
            float4 s1 = *reinterpret_cast<const float4*>(ss + k0 + 4);
            float4 t0 = *reinterpret_cast<const float4*>(ss + 128 + k0);
            float4 t1 = *reinterpret_cast<const float4*>(ss + 128 + k0 + 4);
            float sc[8] = {s0.x, s0.y, s0.z, s0.w, s1.x, s1.y, s1.z, s1.w};
            float sh[8] = {t0.x, t0.y, t0.z, t0.w, t1.x, t1.y, t1.z, t1.w};
            #pragma unroll
            for (int j = 0; j < 8; ++j) v[j] = fmaxf(v[j] * sc[j] + sh[j], 0.f);
        }
        #pragma unroll
        for (int j = 0; j < 8; ++j) a[kt][j] = (short)f2bf(v[j]);
    }

    __syncthreads();

    // ---- MFMA main loop: FULL unroll (compiler pipelines ds_reads) ----
    f32x4 acc[NT] = {};
    #pragma unroll
    for (int kt = 0; kt < 4; ++kt) {
        #pragma unroll
        for (int nt = 0; nt < NT; ++nt) {
            bf16x8 b = *reinterpret_cast<const bf16x8*>(
                sB + ((((nt << 2) + kt) * 64 + lane) << 3));
            acc[nt] = __builtin_amdgcn_mfma_f32_16x16x32_bf16(a[kt], b, acc[nt], 0, 0, 0);
        }
    }

    // ---- epilogue (D: lane l, reg j -> D[m0+(l>>4)*4+j][nt*16+(l&15)]) ----
    int r0 = m0 + ((lane >> 4) << 2);
    int nl = lane & 15;
    #pragma unroll
    for (int nt = 0; nt < NT; ++nt) {
        int col = nt * 16 + nl;
        float bb = (col >= HALF) ? bias[col - HALF] : 0.f;
        #pragma unroll
        for (int j = 0; j < 4; ++j) {
            int r = r0 + j;
            if (r >= N_NODES) continue;
            float vv = acc[nt][j];
            if (MODE == 0) {
                if (col < HALF) outFp8[(long long)r * 128 + col] = (unsigned char)f32_fp8(vv);
                else            outH16[(long long)r * 128 + (col - HALF)] = f2bf(vv + bb);
            } else {
                if (col < HALF) outFp8[(long long)r * 64 + col] = (unsigned char)f32_fp8(vv);
                else            outH16[(long long)r * 64 + (col - HALF)] = f2bf(vv + bb);
            }
        }
    }
}

// ---------------------------------------------------------------------------
// conv1 aggregate: h[n] += mean_{s in N(n)} y1[s]; y1 fp8 (128 B/row),
// h bf16 (256 B/row). Quarter-wave per edge: 16 lanes x uint2 (8 B = 8 ch).
__global__ __launch_bounds__(256) void agg_mean_add_128(
    const int* __restrict__ off, const unsigned short* __restrict__ csr_src,
    const uint2* __restrict__ y8, uint4* __restrict__ h4) {
    int node = blockIdx.x * 4 + (threadIdx.x >> 6);
    if (node >= N_NODES) return;
    int lane = threadIdx.x & 63;
    int grp  = lane >> 4;          // 0..3: which edge of the quad
    int c8   = lane & 15;          // uint2 idx: channels c8*8 .. c8*8+7
    int beg = off[node], end = off[node + 1];
    float s[8] = {0.f, 0.f, 0.f, 0.f, 0.f, 0.f, 0.f, 0.f};
    int i = beg + grp;
    for (; i + 4 < end; i += 8) {
        uint2 v0 = y8[(long long)csr_src[i]     * 16 + c8];
        uint2 v1 = y8[(long long)csr_src[i + 4] * 16 + c8];
        #pragma unroll
        for (int j = 0; j < 4; ++j) {
            s[j]     += fp8_f32((v0.x >> (8 * j)) & 0xFFu) + fp8_f32((v1.x >> (8 * j)) & 0xFFu);
            s[4 + j] += fp8_f32((v0.y >> (8 * j)) & 0xFFu) + fp8_f32((v1.y >> (8 * j)) & 0xFFu);
        }
    }
    for (; i < end; i += 4) {
        uint2 v0 = y8[(long long)csr_src[i] * 16 + c8];
        #pragma unroll
        for (int j = 0; j < 4; ++j) {
            s[j]     += fp8_f32((v0.x >> (8 * j)) & 0xFFu);
            s[4 + j] += fp8_f32((v0.y >> (8 * j)) & 0xFFu);
        }
    }
    #pragma unroll
    for (int j = 0; j < 8; ++j) {
        s[j] += __shfl_down(s[j], 16);
        s[j] += __shfl_down(s[j], 32);
    }
    if (grp == 0) {
        float inv = (end > beg) ? 1.0f / (float)(end - beg) : 0.f;
        uint4 hv = h4[(long long)node * 16 + c8];   // 8 bf16 channels
        hv.x = pack2bf(bf_lo(hv.x) + s[0] * inv, bf_hi(hv.x) + s[1] * inv);
        hv.y = pack2bf(bf_lo(hv.y) + s[2] * inv, bf_hi(hv.y) + s[3] * inv);
        hv.z = pack2bf(bf_lo(hv.z) + s[4] * inv, bf_hi(hv.z) + s[5] * inv);
        hv.w = pack2bf(bf_lo(hv.w) + s[6] * inv, bf_hi(hv.w) + s[7] * inv);
        h4[(long long)node * 16 + c8] = hv;
    }
}

// ---------------------------------------------------------------------------
// BN stats stage A (h bf16): half-wave owns 13 rows; load-all-then-reduce.
__global__ __launch_bounds__(256) void bn_stats_partial(
    const uint2* __restrict__ h2, float* __restrict__ partial) {
    int tid = threadIdx.x;
    int wid = tid >> 6;
    int lane = tid & 63;
    int half = lane >> 5;          // 0/1
    int c4   = lane & 31;          // uint2 idx: channels 4*c4 .. 4*c4+3
    int hw   = (blockIdx.x << 3) + (wid << 1) + half;
    int r0   = hw * BN_RPH;

    uint2 v[BN_RPH];
    #pragma unroll
    for (int j = 0; j < BN_RPH; ++j) {
        int r = r0 + j;
        v[j] = (r < N_NODES) ? h2[(long long)r * 32 + c4] : uint2{0u, 0u};
    }
    float s[4] = {0.f, 0.f, 0.f, 0.f}, q[4] = {0.f, 0.f, 0.f, 0.f};
    #pragma unroll
    for (int j = 0; j < BN_RPH; ++j) {
        float a0 = bf_lo(v[j].x), a1 = bf_hi(v[j].x);
        float a2 = bf_lo(v[j].y), a3 = bf_hi(v[j].y);
        s[0] += a0; q[0] += a0 * a0;
        s[1] += a1; q[1] += a1 * a1;
        s[2] += a2; q[2] += a2 * a2;
        s[3] += a3; q[3] += a3 * a3;
    }
    #pragma unroll
    for (int j = 0; j < 4; ++j) {
        s[j] += __shfl_down(s[j], 32);
        q[j] += __shfl_down(q[j], 32);
    }
    __shared__ float ls[4][32][8];
    if (half == 0) {
        #pragma unroll
        for (int j = 0; j < 4; ++j) { ls[wid][c4][j] = s[j]; ls[wid][c4][4 + j] = q[j]; }
    }
    __syncthreads();
    if (tid < 32) {
        #pragma unroll
        for (int j = 0; j < 8; ++j) {
            float a = ls[0][tid][j] + ls[1][tid][j] + ls[2][tid][j] + ls[3][tid][j];
            partial[blockIdx.x * 256 + (j < 4 ? 0 : 128) + tid * 4 + (j & 3)] = a;
        }
    }
}

// BN stats stage B
__global__ void bn_stats_reduce(const float* __restrict__ partial,
                                float* __restrict__ sums) {
    int t = threadIdx.x;
    int b0 = blockIdx.x * (BN_BLOCKS / 16);
    float a = 0.f;
    #pragma unroll 8
    for (int b = b0; b < b0 + BN_BLOCKS / 16; ++b)
        a += partial[b * 256 + t];
    atomicAdd(&sums[t], a);
}

// scale/shift: ss[c] = gamma*rsqrt(var+eps); ss[128+c] = beta - mu*scale
__global__ void bn_finalize_kernel(const float* __restrict__ sums,
                                   const float* __restrict__ gamma,
                                   const float* __restrict__ beta,
                                   float* __restrict__ ss) {
    int c = threadIdx.x;
    float mu  = sums[c] * (1.0f / N_NODES);
    float var = sums[128 + c] * (1.0f / N_NODES) - mu * mu;
    float sc = gamma[c] * rsqrtf(var + BN_EPS);
    ss[c] = sc;
    ss[128 + c] = beta[c] - mu * sc;
}

// ---------------------------------------------------------------------------
// conv2 aggregate: z[n] = bf16( mean t2l[N(n)] + t2r[n] ); t2l fp8 (64 B/row),
// t2r bf16. Quarter-wave per edge: 16 lanes x uint (4 B = 4 ch) = 64 B/row.
__global__ __launch_bounds__(256) void agg_mean_add_64(
    const int* __restrict__ off, const unsigned short* __restrict__ csr_src,
    const unsigned* __restrict__ t2l4, const uint2* __restrict__ t2r2,
    uint2* __restrict__ z2) {
    int node = blockIdx.x * 4 + (threadIdx.x >> 6);
    if (node >= N_NODES) return;
    int lane = threadIdx.x & 63;
    int grp  = lane >> 4;          // 0..3: which edge of the quad
    int c4   = lane & 15;          // uint idx: channels c4*4 .. c4*4+3
    int beg = off[node], end = off[node + 1];
    float s[4] = {0.f, 0.f, 0.f, 0.f};
    int i = beg + grp;
    for (; i + 4 < end; i += 8) {
        unsigned v0 = t2l4[(long long)csr_src[i]     * 16 + c4];
        unsigned v1 = t2l4[(long long)csr_src[i + 4] * 16 + c4];
        #pragma unroll
        for (int j = 0; j < 4; ++j)
            s[j] += fp8_f32((v0 >> (8 * j)) & 0xFFu) + fp8_f32((v1 >> (8 * j)) & 0xFFu);
    }
    for (; i < end; i += 4) {
        unsigned v0 = t2l4[(long long)csr_src[i] * 16 + c4];
        #pragma unroll
        for (int j = 0; j < 4; ++j)
            s[j] += fp8_f32((v0 >> (8 * j)) & 0xFFu);
    }
    #pragma unroll
    for (int j = 0; j < 4; ++j) {
        s[j] += __shfl_down(s[j], 16);
        s[j] += __shfl_down(s[j], 32);
    }
    if (grp == 0) {
        float inv = (end > beg) ? 1.0f / (float)(end - beg) : 0.f;
        uint2 rv = t2r2[(long long)node * 16 + c4];
        uint2 o;
        o.x = pack2bf(bf_lo(rv.x) + s[0] * inv, bf_hi(rv.x) + s[1] * inv);
        o.y = pack2bf(bf_lo(rv.y) + s[2] * inv, bf_hi(rv.y) + s[3] * inv);
        z2[(long long)node * 16 + c4] = o;
    }
}

// ---------------------------------------------------------------------------
// out[l] = dot(z[src_l], z[dst_l]) over 64 bf16 channels; 16 lanes per label
__global__ void edge_dot_kernel(const int* __restrict__ eli,
                                const unsigned short* __restrict__ z,
                                float* __restrict__ out) {
    long long gid = (long long)blockIdx.x * blockDim.x + threadIdx.x;
    int l = (int)(gid >> 4);
    int lane = (int)(gid & 15);
    if (l >= N_LABEL) return;
    int s = eli[l];
    int d = eli[N_LABEL + l];
    uint2 av = *reinterpret_cast<const uint2*>(z + (long long)s * 64 + lane * 4);
    uint2 bv = *reinterpret_cast<const uint2*>(z + (long long)d * 64 + lane * 4);
    float p = bf_lo(av.x) * bf_lo(bv.x) + bf_hi(av.x) * bf_hi(bv.x)
            + bf_lo(av.y) * bf_lo(bv.y) + bf_hi(av.y) * bf_hi(bv.y);
    p += __shfl_down(p, 8, 16);
    p += __shfl_down(p, 4, 16);
    p += __shfl_down(p, 2, 16);
    p += __shfl_down(p, 1, 16);
    if (lane == 0) out[l] = p;
}

// ---------------------------------------------------------------------------
extern "C" void kernel_launch(void* const* d_in, const int* in_sizes, int n_in,
                              void* d_out, int out_size, void* d_ws, size_t ws_size,
                              hipStream_t stream) {
    const float* x     = (const float*)d_in[0];
    const int*   ei    = (const int*)d_in[1];   // [2, 800000]: row0 src, row1 dst
    const int*   eli   = (const int*)d_in[2];   // [2, 200000]
    const float* W1l   = (const float*)d_in[3];
    const float* W1r   = (const float*)d_in[4];
    const float* b1    = (const float*)d_in[5];
    const float* gamma = (const float*)d_in[6];
    const float* beta  = (const float*)d_in[7];
    const float* W2l   = (const float*)d_in[8];
    const float* W2r   = (const float*)d_in[9];
    const float* b2    = (const float*)d_in[10];
    float* out = (float*)d_out;

    const int* src  = ei;
    const int* dstv = ei + N_EDGES;

    // workspace layout (ints first; all region starts 16B-aligned)
    int* ideg  = (int*)d_ws;             // 50432 (zero-padded to NCHUNK*256)
    int* ioff  = ideg + 50432;           // 50056
    int* ibsum = ioff + 50056;           // 256
    int* iboff = ibsum + 256;            // 256
    unsigned short* icsr = (unsigned short*)(iboff + 256);   // 800000 ushort (1.6 MB)
    unsigned char*  y1  = (unsigned char*)(icsr + 800000);   // 6.4M fp8  (6.4 MB)
    unsigned short* h   = (unsigned short*)(y1 + 6400000);   // 6.4M bf16 (12.8 MB)
    unsigned char*  t2l = (unsigned char*)(h + 6400000);     // 3.2M fp8  (3.2 MB)
    unsigned short* t2r = (unsigned short*)(t2l + 3200000);  // 3.2M bf16
    unsigned short* z   = t2r + 3200000;                     // 3.2M bf16
    float* sums = (float*)(z + 3200000);                     // 256
    float* ss   = sums + 256;                                // 256
    short* Bp1  = (short*)(ss + 256);                        // 32768 bf16 (128x256)
    short* Bp2  = Bp1 + 32768;                               // 16384 bf16 (128x128)
    float* bnpart = (float*)(Bp2 + 16384);                   // 512*256 f32 = 512 KB
    // rank aliases y1's region (3.2 MB < 6.4 MB); consumed by scatter_kernel
    // before mfma_gemm<0> writes y1 (stream order).
    int* irank = (int*)y1;

    // ---- setup: zero ideg+sums, pack Bp1+Bp2 (1 launch) ----
    setup_kernel<<<(50432 + 255) / 256, 256, 0, stream>>>(
        ideg, sums, W1l, W1r, Bp1, W2l, W2r, Bp2);

    // ---- CSR build ----
    hist_kernel<<<(N_EDGES + 255) / 256, 256, 0, stream>>>(dstv, ideg, irank);
    chunk_sum_kernel<<<NCHUNK, 256, 0, stream>>>(ideg, ibsum);
    scan_bsum_kernel<<<1, 256, 0, stream>>>(ibsum, iboff);
    scan_final_kernel<<<NCHUNK, 256, 0, stream>>>(ideg, iboff, ioff);
    scatter_kernel<<<(N_EDGES + 255) / 256, 256, 0, stream>>>(src, dstv, ioff, irank, icsr);

    const int GEMM_GRID = (N_NODES + 127) / 128;   // 391

    // ---- conv1: y1(fp8) = x@W1l, h(bf16) = x@W1r + b1; then h += mean(y1) --
    mfma_gemm<0><<<GEMM_GRID, 512, 0, stream>>>(x, Bp1, b1, ss, y1, h);
    agg_mean_add_128<<<(N_NODES + 3) / 4, 256, 0, stream>>>(
        ioff, icsr, (const uint2*)y1, (uint4*)h);

    // ---- batchnorm stats (two-stage; apply fused into gemm2 A-load) ----
    bn_stats_partial<<<BN_BLOCKS, 256, 0, stream>>>((const uint2*)h, bnpart);
    bn_stats_reduce<<<16, 256, 0, stream>>>(bnpart, sums);
    bn_finalize_kernel<<<1, 128, 0, stream>>>(sums, gamma, beta, ss);

    // ---- conv2: t2l(fp8) = relu(bn(h))@W2l, t2r(bf16) = relu(bn(h))@W2r + b2
    mfma_gemm<1><<<GEMM_GRID, 512, 0, stream>>>(h, Bp2, b2, ss, t2l, t2r);
    agg_mean_add_64<<<(N_NODES + 3) / 4, 256, 0, stream>>>(
        ioff, icsr, (const unsigned*)t2l, (const uint2*)t2r, (uint2*)z);

    // ---- edge dot readout ----
    edge_dot_kernel<<<((long long)N_LABEL * 16 + 255) / 256, 256, 0, stream>>>(eli, z, out);
}